// Round 1
// baseline (463.133 us; speedup 1.0000x reference)
//
#include <hip/hip_runtime.h>
#include <math.h>

// ---------------- Cl(3,0,1) compile-time algebra helpers ----------------
constexpr int cpopc(int x){ int c=0; while(x){ c += x&1; x >>= 1; } return c; }

// sign of e_a * e_b geometric product (0 if it hits the null direction e3)
constexpr float csign(int a, int b){
    if (a & b & 8) return 0.0f;   // e3^2 = 0 (metric {1,1,1,0})
    int s = 0;
    for (int t = a >> 1; t; t >>= 1) s += cpopc(t & b);
    return (s & 1) ? -1.0f : 1.0f;
}

// even subalgebra (grades 0,2,4) blade indices and inverse map
__device__ constexpr int EVEN[8] = {0,3,5,6,9,10,12,15};
__device__ constexpr int EIDX[16] = {0,-1,-1,1,-1,2,3,-1,-1,4,5,-1,6,-1,-1,7};
// reverse signs on even blades: g=0:+, g=2:-, g=4:+
__device__ constexpr float REVE[8] = {1.f,-1.f,-1.f,-1.f,-1.f,-1.f,-1.f,1.f};

#define WS_STRIDE 288   // floats per batch row l in workspace: 256 (T) + 20 (v1/v2 interleaved) + pad

// ---------------- setup: per-l motor -> 16x16 matrix T, color tables ----------------
__global__ void setup_kernel(const float* __restrict__ instr,
                             const float* __restrict__ remap,   // [K,10,10]
                             const float* __restrict__ selw,    // [K,2]
                             const float* __restrict__ selb,    // [K]
                             float* __restrict__ ws,
                             int B, int K) {
    const int l = blockIdx.x * blockDim.x + threadIdx.x;
    if (l >= B) return;
    const float* ins = instr + l * 16;

    // x = -0.5 * grade2(instruction), even-subalgebra coords (bivectors are m=1..6)
    float bv[8];
    bv[0] = 0.f; bv[7] = 0.f;
    #pragma unroll
    for (int m = 1; m < 7; m++) bv[m] = -0.5f * ins[EVEN[m]];

    // Taylor exp, 16 terms, even subalgebra only
    float term[8], acc[8];
    #pragma unroll
    for (int m = 0; m < 8; m++){ term[m] = (m==0) ? 1.f : 0.f; acc[m] = term[m]; }
    #pragma unroll
    for (int n = 1; n < 16; n++){
        float nt[8];
        #pragma unroll
        for (int m = 0; m < 8; m++) nt[m] = 0.f;
        #pragma unroll
        for (int ia = 0; ia < 8; ia++){
            #pragma unroll
            for (int ib = 0; ib < 8; ib++){
                const float s = csign(EVEN[ia], EVEN[ib]);   // compile-time constant
                if (s != 0.f) nt[EIDX[EVEN[ia] ^ EVEN[ib]]] += s * term[ia] * bv[ib];
            }
        }
        const float inv = 1.0f / (float)n;
        #pragma unroll
        for (int m = 0; m < 8; m++){ term[m] = nt[m] * inv; acc[m] += term[m]; }
    }

    // M and ~M (even coords), pairwise products
    float P[64];
    #pragma unroll
    for (int ia = 0; ia < 8; ia++)
        #pragma unroll
        for (int ib = 0; ib < 8; ib++)
            P[ia*8+ib] = acc[ia] * (acc[ib] * REVE[ib]);

    // T[j][k] = sum_{a,b even} csign(a,j)*csign(a^j,b) * M[a]*Mrev[b], k = j^a^b
    float* o = ws + (size_t)l * WS_STRIDE;
    #pragma unroll
    for (int j = 0; j < 16; j++){
        float Trow[16];
        #pragma unroll
        for (int k = 0; k < 16; k++) Trow[k] = 0.f;
        #pragma unroll
        for (int ia = 0; ia < 8; ia++){
            const int A = EVEN[ia];
            const float sa = csign(A, j);
            if (sa != 0.f){
                #pragma unroll
                for (int ib = 0; ib < 8; ib++){
                    const int Bb = EVEN[ib];
                    const float s = sa * csign(A ^ j, Bb);
                    if (s != 0.f) Trow[j ^ A ^ Bb] += s * P[ia*8+ib];
                }
            }
        }
        #pragma unroll
        for (int k = 0; k < 16; k++) o[j*16 + k] = Trow[k];
    }

    // ---- color tables: softmax selector weights, fold blended into v1/v2 ----
    const float s0 = ins[0], s1 = ins[15];
    float w[8];                       // K <= 8 (K=4 here)
    float mx = -1e30f;
    for (int k = 0; k < K; k++){
        w[k] = s0 * selw[2*k] + s1 * selw[2*k+1] + selb[k];
        mx = fmaxf(mx, w[k]);
    }
    float Z = 0.f;
    for (int k = 0; k < K; k++){ w[k] = __expf(w[k] - mx); Z += w[k]; }
    const float rZ = 1.f / Z;
    for (int k = 0; k < K; k++) w[k] *= rZ;

    // v1[i] = sum_j blended[i][j]*j/9 ; v2[i] = blended[i][0]; interleaved float2
    for (int i = 0; i < 10; i++){
        float a1 = 0.f, a2 = 0.f;
        for (int k = 0; k < K; k++){
            const float* rk = remap + (size_t)(k*10 + i) * 10;
            float rd = 0.f;
            #pragma unroll
            for (int j = 0; j < 10; j++) rd += rk[j] * (float)j;
            a1 += w[k] * rd;
            a2 += w[k] * rk[0];
        }
        o[256 + 2*i]     = a1 * (1.f / 9.f);
        o[256 + 2*i + 1] = a2;
    }
}

// ---------------- main streaming kernel ----------------
#define TPB 256
#define EPT 4

__global__ __launch_bounds__(TPB) void apply_kernel(
    const float* __restrict__ state, const float* __restrict__ ws,
    float* __restrict__ out, int N) {
    const int l = blockIdx.y;
    __shared__ float4 sT[64];     // T[j][k] as 64 float4s
    __shared__ float2 svc[10];    // (v1[i], v2[i])
    const float* wsl = ws + (size_t)l * WS_STRIDE;
    {
        const int t = threadIdx.x;
        if (t < 64) sT[t] = reinterpret_cast<const float4*>(wsl)[t];
        if (t >= 64 && t < 74) svc[t-64] = reinterpret_cast<const float2*>(wsl + 256)[t-64];
    }
    __syncthreads();

    const int tid    = blockIdx.x * TPB + threadIdx.x;
    const int stride = gridDim.x * TPB;
    const float4* __restrict__ sp = reinterpret_cast<const float4*>(state) + (size_t)l * N * 4;
    float4*       __restrict__ op = reinterpret_cast<float4*>(out)        + (size_t)l * N * 4;

    int nn[EPT];
    float x[EPT][16];
    #pragma unroll
    for (int e = 0; e < EPT; e++){
        nn[e] = tid + e * stride;
        if (nn[e] < N){
            #pragma unroll
            for (int c = 0; c < 4; c++){
                const float4 v = sp[(size_t)nn[e]*4 + c];
                x[e][4*c+0] = v.x; x[e][4*c+1] = v.y; x[e][4*c+2] = v.z; x[e][4*c+3] = v.w;
            }
        } else {
            #pragma unroll
            for (int k = 0; k < 16; k++) x[e][k] = 0.f;
        }
    }

    float y[EPT][16];
    #pragma unroll
    for (int e = 0; e < EPT; e++)
        #pragma unroll
        for (int k = 0; k < 16; k++) y[e][k] = 0.f;

    #pragma unroll
    for (int j = 0; j < 16; j++){
        const float4 t0 = sT[4*j+0], t1 = sT[4*j+1], t2 = sT[4*j+2], t3 = sT[4*j+3];
        #pragma unroll
        for (int e = 0; e < EPT; e++){
            const float xv = x[e][j];
            y[e][0]  += xv * t0.x; y[e][1]  += xv * t0.y; y[e][2]  += xv * t0.z; y[e][3]  += xv * t0.w;
            y[e][4]  += xv * t1.x; y[e][5]  += xv * t1.y; y[e][6]  += xv * t1.z; y[e][7]  += xv * t1.w;
            y[e][8]  += xv * t2.x; y[e][9]  += xv * t2.y; y[e][10] += xv * t2.z; y[e][11] += xv * t2.w;
            y[e][12] += xv * t3.x; y[e][13] += xv * t3.y; y[e][14] += xv * t3.z; y[e][15] += xv * t3.w;
        }
    }

    // color unit: stable softmax over 10 centers, folded into two dot products
    #pragma unroll
    for (int e = 0; e < EPT; e++){
        const float raw  = y[e][0] * 9.f;
        const float nc   = fminf(fmaxf(rintf(raw), 0.f), 9.f);   // nearest center => max logit
        const float dmin = raw - nc;
        const float mlog = -4.f * dmin * dmin;
        float Z = 0.f, c1 = 0.f, c2 = 0.f;
        #pragma unroll
        for (int i = 0; i < 10; i++){
            const float d  = raw - (float)i;
            const float ev = __expf(-4.f*d*d - mlog);
            const float2 v = svc[i];
            Z += ev; c1 += ev * v.x; c2 += ev * v.y;
        }
        const float rZ = 1.f / Z;
        y[e][0]  = c1 * rZ;          // new_color (v1 already includes /9)
        y[e][15] = 1.f - c2 * rZ;    // new_occupancy
    }

    #pragma unroll
    for (int e = 0; e < EPT; e++){
        if (nn[e] < N){
            #pragma unroll
            for (int c = 0; c < 4; c++)
                op[(size_t)nn[e]*4 + c] = make_float4(y[e][4*c], y[e][4*c+1], y[e][4*c+2], y[e][4*c+3]);
        }
    }
}

extern "C" void kernel_launch(void* const* d_in, const int* in_sizes, int n_in,
                              void* d_out, int out_size, void* d_ws, size_t ws_size,
                              hipStream_t stream) {
    const float* state = (const float*)d_in[0];
    const float* instr = (const float*)d_in[1];
    const float* remap = (const float*)d_in[2];
    const float* selw  = (const float*)d_in[3];
    const float* selb  = (const float*)d_in[4];
    float* ws  = (float*)d_ws;
    float* out = (float*)d_out;

    const int B = in_sizes[1] / 16;          // 32
    const int N = in_sizes[0] / (16 * B);    // 100000
    const int K = in_sizes[4];               // 4

    setup_kernel<<<dim3((B + 63) / 64), 64, 0, stream>>>(instr, remap, selw, selb, ws, B, K);

    const int groups = (N + TPB * EPT - 1) / (TPB * EPT);   // 98
    apply_kernel<<<dim3(groups, B), TPB, 0, stream>>>(state, ws, out, N);
}